// Round 2
// baseline (205.867 us; speedup 1.0000x reference)
//
#include <hip/hip_runtime.h>
#include <math.h>

// Problem constants (from reference)
#define T_LEN   1024
#define N_INPUT 1024
#define H_DIM   128
#define BATCH   2
#define TC      32           // scan chunk length (pass 2)
#define NC      32           // number of chunks (TC*NC == T_LEN)

// Output layout (verified R6): d_out holds ONLY the real part:
//   out[t][b][j][k] row-major, 33,554,432 float32.
#define PLANE   ((size_t)T_LEN * BATCH * H_DIM * H_DIM)  // 33,554,432
#define TSTRIDE ((size_t)BATCH * H_DIM * H_DIM)          // 32,768 per t

// native clang vector for nontemporal builtins (HIP float4 is a class type)
typedef float vfloat4 __attribute__((ext_vector_type(4)));

// bu stash: parked in out's t in [1008,1024) slots. Cell (b,j,t,comp) lives at
//   (1008 + (t>>6))*TSTRIDE + b*16384 + j*128 + (t&63)*2 + comp
// Block (b,j) of pass 2 reads ONLY its own (b,j) columns, which it alone
// overwrites at the end of its scan -> race-free across the kernel boundary.

// ---------------------------------------------------------------------------
// Pass 1: bu[b][j][t] = c[j] * dot(b_re[j,:]+i*b_im[j,:], u[b,t,:])
// Grid 256 = (b, tg of 8 rows). 1024 threads = (j2 0..63, c16 0..15):
// each thread owns TWO j rows (j2, j2+64) so every LDS u-read feeds 16 fma
// instead of 8 -> halves ds_read_b128 issue (was the per-CU bottleneck).
// ---------------------------------------------------------------------------
__global__ __launch_bounds__(1024)
void bu_kernel(const float* __restrict__ u,
               const float* __restrict__ delta_p,
               const float* __restrict__ lre,
               const float* __restrict__ lim,
               const float* __restrict__ b_re,
               const float* __restrict__ b_im,
               float* __restrict__ out) {
    __shared__ __align__(16) float su[8][N_INPUT];   // 8 u rows   (32 KB)
    __shared__ float sred[2048];                     // bu results (8 KB)

    int blk = blockIdx.x;                // b*128 + tg
    int b   = blk >> 7;
    int tg  = blk & 127;
    int tid = threadIdx.x;
    int j2  = tid >> 4;                  // 0..63
    int c16 = tid & 15;                  // 16-way split of i
    int jA  = j2;
    int jB  = j2 + 64;

    // stage u rows t = tg*8 .. tg*8+7 (coalesced float4)
    const float4* g4 = (const float4*)(u + ((size_t)b * T_LEN + (size_t)tg * 8) * N_INPUT);
    float4* s4 = (float4*)su;
    s4[tid]        = g4[tid];
    s4[tid + 1024] = g4[tid + 1024];
    __syncthreads();

    const float4* br4 = (const float4*)b_re;
    const float4* bi4 = (const float4*)b_im;
    int baseA = jA * 256 + c16;          // float4 index of row jA, chunk c16
    int baseB = jB * 256 + c16;

    float arA[8], aiA[8], arB[8], aiB[8];
#pragma unroll
    for (int t = 0; t < 8; ++t) { arA[t] = 0.f; aiA[t] = 0.f; arB[t] = 0.f; aiB[t] = 0.f; }

    for (int ii = 0; ii < 16; ++ii) {
        float4 brA = br4[baseA + ii * 16];
        float4 biA = bi4[baseA + ii * 16];
        float4 brB = br4[baseB + ii * 16];
        float4 biB = bi4[baseB + ii * 16];
        int w = (ii * 16 + c16) * 4;     // float offset in a row
#pragma unroll
        for (int t = 0; t < 8; ++t) {
            float4 uv = *(const float4*)&su[t][w];   // 4-lane broadcast, no conflict
            arA[t] += brA.x * uv.x + brA.y * uv.y + brA.z * uv.z + brA.w * uv.w;
            aiA[t] += biA.x * uv.x + biA.y * uv.y + biA.z * uv.z + biA.w * uv.w;
            arB[t] += brB.x * uv.x + brB.y * uv.y + brB.z * uv.z + brB.w * uv.w;
            aiB[t] += biB.x * uv.x + biB.y * uv.y + biB.z * uv.z + biB.w * uv.w;
        }
    }

    // c[j] = (lambda_bar - 1) / lambda, for both owned rows
    float delta = delta_p[0];
    float crA, ciA, crB, ciB;
    {
        float ar = lre[jA], ai = lim[jA];
        float e = expf(ar * delta);
        float s_, co;
        sincosf(ai * delta, &s_, &co);
        float nr = e * co - 1.0f, ni = e * s_, dd = ar * ar + ai * ai;
        crA = (nr * ar + ni * ai) / dd;
        ciA = (ni * ar - nr * ai) / dd;
    }
    {
        float ar = lre[jB], ai = lim[jB];
        float e = expf(ar * delta);
        float s_, co;
        sincosf(ai * delta, &s_, &co);
        float nr = e * co - 1.0f, ni = e * s_, dd = ar * ar + ai * ai;
        crB = (nr * ar + ni * ai) / dd;
        ciB = (ni * ar - nr * ai) / dd;
    }

#pragma unroll
    for (int t = 0; t < 8; ++t) {
        float rA = arA[t], iA = aiA[t], rB = arB[t], iB = aiB[t];
#pragma unroll
        for (int m = 1; m <= 8; m <<= 1) {
            rA += __shfl_xor(rA, m);  iA += __shfl_xor(iA, m);
            rB += __shfl_xor(rB, m);  iB += __shfl_xor(iB, m);
        }
        if (c16 == 0) {
            sred[jA * 16 + t * 2]     = crA * rA - ciA * iA;
            sred[jA * 16 + t * 2 + 1] = crA * iA + ciA * rA;
            sred[jB * 16 + t * 2]     = crB * rB - ciB * iB;
            sred[jB * 16 + t * 2 + 1] = crB * iB + ciB * rB;
        }
    }
    __syncthreads();

    // write stash: block's region = row (1008+tg>>3), k in (tg&7)*16+[0,16)
    size_t wb = (size_t)(1008 + (tg >> 3)) * TSTRIDE + (size_t)b * 16384 + (size_t)(tg & 7) * 16;
#pragma unroll
    for (int r = 0; r < 2; ++r) {
        int e2 = tid + r * 1024;         // element [j=e2>>4][m=e2&15]
        out[wb + (size_t)(e2 >> 4) * 128 + (e2 & 15)] = sred[e2];
    }
}

// ---------------------------------------------------------------------------
// Pass 2: chunked scan. Grid 256 = (b,j). 1024 threads = 32 chunks x 32
// k-groups; each thread owns FOUR k states. vs previous version:
//   - serial dep chain per thread 256 -> 64 steps
//   - LDS read wave-insts drop 8x (float4 bu reads + TC 128->32)
//   - stores are float4 nontemporal (1024 B/wave-inst, 4x fewer stores)
// ---------------------------------------------------------------------------
__global__ __launch_bounds__(1024)
void scan_kernel(const float* __restrict__ delta_p,
                 const float* __restrict__ lre,
                 const float* __restrict__ lim,
                 float* out) {
    __shared__ __align__(16) float2 sbu[T_LEN];   // bu row    (8 KB)
    __shared__ float2 sP[NC][H_DIM];              // partials  (32 KB)
    __shared__ float2 sX[NC][H_DIM];              // starts    (32 KB)

    int blk = blockIdx.x;                // b*128 + j
    int b   = blk >> 7;
    int j   = blk & 127;
    int tid = threadIdx.x;
    int kg  = tid & 31;                  // k-group: k = kg*4 .. kg*4+3
    int c   = tid >> 5;                  // chunk 0..31
    int k0  = kg * 4;

    // load this (b,j)'s bu row from the stash (coalesced float2)
    {
        int s = tid >> 6, w = tid & 63;  // t = s*64 + w
        const float* p = out + (size_t)(1008 + s) * TSTRIDE + (size_t)b * 16384
                             + (size_t)j * 128 + (size_t)w * 2;
        sbu[s * 64 + w] = *(const float2*)p;
    }

    // lambda_bar for this thread's 4 k values
    float delta = delta_p[0];
    float lbr[4], lbi[4];
#pragma unroll
    for (int q = 0; q < 4; ++q) {
        float ar = lre[k0 + q], ai = lim[k0 + q];
        float e = expf(ar * delta);
        float s_, co;
        sincosf(ai * delta, &s_, &co);
        lbr[q] = e * co;
        lbi[q] = e * s_;
    }
    __syncthreads();

    const float4* sbu4 = (const float4*)sbu;

    // phase 1: per-chunk partial (4 k states, bu read as float4 = 2 steps)
    {
        float pr[4] = {0.f, 0.f, 0.f, 0.f}, pi[4] = {0.f, 0.f, 0.f, 0.f};
        int t0 = c * TC;
#pragma unroll 4
        for (int s2 = 0; s2 < TC; s2 += 2) {
            float4 bb = sbu4[(t0 + s2) >> 1];
#pragma unroll
            for (int q = 0; q < 4; ++q) {
                float nr = lbr[q] * pr[q] - lbi[q] * pi[q] + bb.x;
                float ni = lbr[q] * pi[q] + lbi[q] * pr[q] + bb.y;
                pr[q] = nr; pi[q] = ni;
            }
#pragma unroll
            for (int q = 0; q < 4; ++q) {
                float nr = lbr[q] * pr[q] - lbi[q] * pi[q] + bb.z;
                float ni = lbr[q] * pi[q] + lbi[q] * pr[q] + bb.w;
                pr[q] = nr; pi[q] = ni;
            }
        }
#pragma unroll
        for (int q = 0; q < 4; ++q) sP[c][k0 + q] = make_float2(pr[q], pi[q]);
    }
    __syncthreads();

    // phase 2: chunk-boundary combine on 128 threads: G = lambda^32
    if (tid < H_DIM) {
        int k = tid;
        float ar = lre[k], ai = lim[k];
        float e = expf(ar * delta);
        float s_, co;
        sincosf(ai * delta, &s_, &co);
        float gr = e * co, gi = e * s_;
#pragma unroll
        for (int q = 0; q < 5; ++q) {    // ^32 = 5 squarings
            float tr = gr * gr - gi * gi;
            float ti = 2.0f * gr * gi;
            gr = tr; gi = ti;
        }
        float xr = 0.0f, xi = 0.0f;
#pragma unroll
        for (int cc = 0; cc < NC; ++cc) {
            sX[cc][k] = make_float2(xr, xi);
            float2 p = sP[cc][k];
            float nr = gr * xr - gi * xi + p.x;
            float ni = gr * xi + gi * xr + p.y;
            xr = nr; xi = ni;
        }
    }
    __syncthreads();

    // phase 3: final scan within chunk; store REAL part as float4 (nontemporal)
    {
        float xr[4], xi[4];
#pragma unroll
        for (int q = 0; q < 4; ++q) {
            float2 x0 = sX[c][k0 + q];
            xr[q] = x0.x; xi[q] = x0.y;
        }
        int t0 = c * TC;
        float* outp = out + (size_t)t0 * TSTRIDE + (size_t)b * 16384
                          + (size_t)j * 128 + k0;
#pragma unroll 4
        for (int s2 = 0; s2 < TC; s2 += 2) {
            float4 bb = sbu4[(t0 + s2) >> 1];
#pragma unroll
            for (int q = 0; q < 4; ++q) {
                float nr = lbr[q] * xr[q] - lbi[q] * xi[q] + bb.x;
                float ni = lbr[q] * xi[q] + lbi[q] * xr[q] + bb.y;
                xr[q] = nr; xi[q] = ni;
            }
            vfloat4 v0 = (vfloat4){xr[0], xr[1], xr[2], xr[3]};
#pragma unroll
            for (int q = 0; q < 4; ++q) {
                float nr = lbr[q] * xr[q] - lbi[q] * xi[q] + bb.z;
                float ni = lbr[q] * xi[q] + lbi[q] * xr[q] + bb.w;
                xr[q] = nr; xi[q] = ni;
            }
            vfloat4 v1 = (vfloat4){xr[0], xr[1], xr[2], xr[3]};
            __builtin_nontemporal_store(v0, (vfloat4*)(outp + (size_t)s2 * TSTRIDE));
            __builtin_nontemporal_store(v1, (vfloat4*)(outp + (size_t)(s2 + 1) * TSTRIDE));
        }
    }
}

// ---------------------------------------------------------------------------
extern "C" void kernel_launch(void* const* d_in, const int* in_sizes, int n_in,
                              void* d_out, int out_size, void* d_ws, size_t ws_size,
                              hipStream_t stream) {
    const float* u      = (const float*)d_in[0];
    const float* delta  = (const float*)d_in[1];
    const float* lre    = (const float*)d_in[2];
    const float* lim    = (const float*)d_in[3];
    const float* b_re   = (const float*)d_in[4];
    const float* b_im   = (const float*)d_in[5];
    float* out = (float*)d_out;

    if ((size_t)out_size >= PLANE) {
        bu_kernel<<<BATCH * 128, 1024, 0, stream>>>(u, delta, lre, lim, b_re, b_im, out);
        scan_kernel<<<BATCH * H_DIM, 1024, 0, stream>>>(delta, lre, lim, out);
    }
}

// Round 4
// 200.256 us; speedup vs baseline: 1.0280x; 1.0280x over previous
//
#include <hip/hip_runtime.h>
#include <math.h>

// Problem constants (from reference)
#define T_LEN   1024
#define N_INPUT 1024
#define H_DIM   128
#define BATCH   2
#define TC      128          // scan chunk length
#define NC      8            // number of chunks (TC*NC == T_LEN)

// Output layout (verified R6): d_out holds ONLY the real part:
//   out[t][b][j][k] row-major, 33,554,432 float32.
#define PLANE   ((size_t)T_LEN * BATCH * H_DIM * H_DIM)  // 33,554,432
#define TSTRIDE ((size_t)BATCH * H_DIM * H_DIM)          // 32,768 per t

// bu stash: parked in out's t in [1008,1024) slots. Cell (b,j,t,comp) lives at
//   (1008 + (t>>6))*TSTRIDE + b*16384 + j*128 + (t&63)*2 + comp
// Block (b,j) of pass 2 reads ONLY its own (b,j) columns, which it alone
// overwrites at the end of its scan -> race-free across the kernel boundary.

// ---------------------------------------------------------------------------
// Pass 1: bu[b][j][t] = c[j] * dot(b_re[j,:]+i*b_im[j,:], u[b,t,:])
// Grid 256 = (b, tg of 8 rows). 1024 threads = (j, c8): 8-way i-split.
// ---------------------------------------------------------------------------
__global__ __launch_bounds__(1024)
void bu_kernel(const float* __restrict__ u,
               const float* __restrict__ delta_p,
               const float* __restrict__ lre,
               const float* __restrict__ lim,
               const float* __restrict__ b_re,
               const float* __restrict__ b_im,
               float* __restrict__ out) {
    __shared__ float su[8][N_INPUT];     // 8 u rows      (32 KB)
    __shared__ float sred[2048];         // bu results    (8 KB)

    int blk = blockIdx.x;                // b*128 + tg
    int b   = blk >> 7;
    int tg  = blk & 127;
    int tid = threadIdx.x;
    int j   = tid >> 3;                  // 0..127
    int c8  = tid & 7;                   // 8-way split of i

    // stage u rows t = tg*8 .. tg*8+7 (coalesced float4)
    const float4* g4 = (const float4*)(u + ((size_t)b * T_LEN + (size_t)tg * 8) * N_INPUT);
    float4* s4 = (float4*)su;
    s4[tid]        = g4[tid];
    s4[tid + 1024] = g4[tid + 1024];
    __syncthreads();

    const float4* br4 = (const float4*)b_re;
    const float4* bi4 = (const float4*)b_im;
    int bbase = j * 256 + c8;            // float4 index of row j, chunk c8

    float accr[8], acci[8];
#pragma unroll
    for (int t = 0; t < 8; ++t) { accr[t] = 0.0f; acci[t] = 0.0f; }

    for (int ii = 0; ii < 32; ++ii) {
        float4 br = br4[bbase + ii * 8];
        float4 bi = bi4[bbase + ii * 8];
        int w = (ii * 8 + c8) * 4;       // float offset in a row
#pragma unroll
        for (int t = 0; t < 8; ++t) {
            float4 uv = *(const float4*)&su[t][w];   // 8-lane broadcast, no conflict
            accr[t] += br.x * uv.x + br.y * uv.y + br.z * uv.z + br.w * uv.w;
            acci[t] += bi.x * uv.x + bi.y * uv.y + bi.z * uv.z + bi.w * uv.w;
        }
    }

    // c[j] = (lambda_bar - 1) / lambda
    float delta = delta_p[0];
    float ar = lre[j], ai = lim[j];
    float e = expf(ar * delta);
    float s_, co;
    sincosf(ai * delta, &s_, &co);
    float lbr = e * co, lbi = e * s_;
    float nr = lbr - 1.0f, ni = lbi, dd = ar * ar + ai * ai;
    float cr = (nr * ar + ni * ai) / dd, ci = (ni * ar - nr * ai) / dd;

#pragma unroll
    for (int t = 0; t < 8; ++t) {
        float r = accr[t], i = acci[t];
        r += __shfl_xor(r, 1);  i += __shfl_xor(i, 1);
        r += __shfl_xor(r, 2);  i += __shfl_xor(i, 2);
        r += __shfl_xor(r, 4);  i += __shfl_xor(i, 4);
        if (c8 == 0) {
            sred[j * 16 + t * 2]     = cr * r - ci * i;
            sred[j * 16 + t * 2 + 1] = cr * i + ci * r;
        }
    }
    __syncthreads();

    // write stash: block's region = rows (1008+tg>>3), k in (tg&7)*16+[0,16)
    size_t wb = (size_t)(1008 + (tg >> 3)) * TSTRIDE + (size_t)b * 16384 + (size_t)(tg & 7) * 16;
#pragma unroll
    for (int r = 0; r < 2; ++r) {
        int e2 = tid + r * 1024;         // element [j=e2>>4][m=e2&15]
        out[wb + (size_t)(e2 >> 4) * 128 + (e2 & 15)] = sred[e2];
    }
}

// ---------------------------------------------------------------------------
// Pass 2: chunked scan (R6 structure minus dot phase).
// Grid 256 = (b,j), 1024 threads = 8 chunks x 128 k-lanes.
// ---------------------------------------------------------------------------
__global__ __launch_bounds__(1024)
void scan_kernel(const float* __restrict__ delta_p,
                 const float* __restrict__ lre,
                 const float* __restrict__ lim,
                 float* out) {
    __shared__ float2 sbu[T_LEN];        // bu row      (8 KB)
    __shared__ float2 sP[NC][H_DIM];     // partials    (8 KB)
    __shared__ float2 sX[NC][H_DIM];     // starts      (8 KB)

    int blk = blockIdx.x;                // b*128 + j
    int b   = blk >> 7;
    int j   = blk & 127;
    int tid = threadIdx.x;
    int k   = tid & 127;
    int c   = tid >> 7;

    // load this (b,j)'s bu row from the stash (coalesced float2)
    {
        int s = tid >> 6, w = tid & 63;  // t = s*64 + w
        const float* p = out + (size_t)(1008 + s) * TSTRIDE + (size_t)b * 16384
                             + (size_t)j * 128 + (size_t)w * 2;
        sbu[s * 64 + w] = *(const float2*)p;
    }

    // lambda_bar for this k
    float delta = delta_p[0];
    float ar = lre[k], ai = lim[k];
    float e = expf(ar * delta);
    float s_, co;
    sincosf(ai * delta, &s_, &co);
    float lbr = e * co, lbi = e * s_;
    __syncthreads();

    // per-chunk partial
    {
        float pr = 0.0f, pi = 0.0f;
        int t0 = c * TC;
        for (int s2 = 0; s2 < TC; ++s2) {
            float2 bu = sbu[t0 + s2];
            float nr2 = lbr * pr - lbi * pi + bu.x;
            float ni2 = lbr * pi + lbi * pr + bu.y;
            pr = nr2; pi = ni2;
        }
        sP[c][k] = make_float2(pr, pi);
    }
    __syncthreads();

    // chunk-boundary combine on 128 threads: G = lambda^128
    if (tid < H_DIM) {
        float gr = lbr, gi = lbi;
#pragma unroll
        for (int q = 0; q < 7; ++q) {
            float tr = gr * gr - gi * gi;
            float ti = 2.0f * gr * gi;
            gr = tr; gi = ti;
        }
        float xr = 0.0f, xi = 0.0f;
#pragma unroll
        for (int cc = 0; cc < NC; ++cc) {
            sX[cc][tid] = make_float2(xr, xi);
            float2 p = sP[cc][tid];
            float nr2 = gr * xr - gi * xi + p.x;
            float ni2 = gr * xi + gi * xr + p.y;
            xr = nr2; xi = ni2;
        }
    }
    __syncthreads();

    // final scan within chunk; store REAL part only (nontemporal)
    {
        float2 x0 = sX[c][k];
        float xr = x0.x, xi = x0.y;
        int t0 = c * TC;
        float* outr = out + ((size_t)b * H_DIM + j) * H_DIM + k + (size_t)t0 * TSTRIDE;
        for (int s2 = 0; s2 < TC; ++s2) {
            float2 bu = sbu[t0 + s2];
            float nr2 = lbr * xr - lbi * xi + bu.x;
            float ni2 = lbr * xi + lbi * xr + bu.y;
            xr = nr2; xi = ni2;
            __builtin_nontemporal_store(xr, outr + (size_t)s2 * TSTRIDE);
        }
    }
}

// ---------------------------------------------------------------------------
extern "C" void kernel_launch(void* const* d_in, const int* in_sizes, int n_in,
                              void* d_out, int out_size, void* d_ws, size_t ws_size,
                              hipStream_t stream) {
    const float* u      = (const float*)d_in[0];
    const float* delta  = (const float*)d_in[1];
    const float* lre    = (const float*)d_in[2];
    const float* lim    = (const float*)d_in[3];
    const float* b_re   = (const float*)d_in[4];
    const float* b_im   = (const float*)d_in[5];
    float* out = (float*)d_out;

    if ((size_t)out_size >= PLANE) {
        bu_kernel<<<BATCH * 128, 1024, 0, stream>>>(u, delta, lre, lim, b_re, b_im, out);
        scan_kernel<<<BATCH * H_DIM, 1024, 0, stream>>>(delta, lre, lim, out);
    }
}